// Round 6
// baseline (67.974 us; speedup 1.0000x reference)
//
#include <hip/hip_runtime.h>
#include <math.h>

// Chamfer distance, B=2, N=M=8192, C=3, fp32 — FUSED: each d(s_i,t_j) computed once,
// feeding both row-min (src->tgt) and col-min (tgt->src).
// d_out (float32): [loss_src, loss_dst, indices1 (B*N), indices2 (B*M)]
// ws: rowpart u64[128][16384] (one entry per (colblock,row), written once, no init),
//     colpart u64[8][16384]   (one entry per (rowblock,col), written once, no init),
//     then float pr[64], pc[4096].
//
// NOTE (R1): do NOT fuse the final combine via a last-block ticket — per-block
// __threadfence() on multi-XCD gfx950 = L2 writeback per block (4160 blocks -> 268 us).
// NOTE (R2): CT=128 (4 blocks/CU) LOST 2 us vs CT=64 (8 blocks/CU): occupancy beats
// atomic-traffic reduction.
// NOTE (R3): __builtin_amdgcn_ds_swizzle pattern must be a literal -> template param.
// NOTE (R4): fold micro-opts flat — not fold-bound.
// NOTE (R5): packed fp32 cut VALUBusy 78->58% with dur FLAT -> cd_tile is NOT
// issue-bound; it is latency-bound (occupancy ~29%, HBM 7%). This round: replace all
// contended device atomicMin (2.1M lane-atomics, 128-way contention, cross-XCD) with
// write-once partial stores + u64-min sweep in cd_fin; delete cd_init entirely.

static constexpr int Bn = 2;
static constexpr int Nn = 8192;
static constexpr int THR = 256;    // 4 waves per block
static constexpr int QPL = 4;      // rows per lane
static constexpr int RT = 1024;    // rows per block; wave w owns [rbase+256w, +256)
static constexpr int WROWS = 256;  // rows per wave (QPL*64)
static constexpr int CT = 64;      // cols staged per block (8 blocks/CU, R2 lesson)
static constexpr int TB = 8;       // cols per register batch (4 f32x2 pairs)
static constexpr int CB = 4096;    // col-mode blocks in cd_fin (4 cols/block, 1 wave/col)
static constexpr int NRB = Nn / RT;   // 8 row-blocks  (colpart contenders)
static constexpr int NCB = Nn / CT;   // 128 col-blocks (rowpart contenders)
static constexpr int ENT = Bn * Nn;   // 16384 entries per partial plane

typedef __attribute__((ext_vector_type(2))) float f32x2;

__device__ __forceinline__ f32x2 pk_add(f32x2 a, f32x2 b) {
    f32x2 r;
    asm("v_pk_add_f32 %0, %1, %2" : "=v"(r) : "v"(a), "v"(b));
    return r;
}
__device__ __forceinline__ f32x2 pk_mul(f32x2 a, f32x2 b) {
    f32x2 r;
    asm("v_pk_mul_f32 %0, %1, %2" : "=v"(r) : "v"(a), "v"(b));
    return r;
}
__device__ __forceinline__ f32x2 fmin2(f32x2 a, f32x2 b) {
    f32x2 r;
    r.x = fminf(a.x, b.x);
    r.y = fminf(a.y, b.y);
    return r;
}
// Squared distances of TWO target points vs one source point whose NEGATED coords are
// broadcast. Per component: ((dx*dx+dy*dy)+dz*dz), each op IEEE-rounded -> bitwise
// identical to scalar dist3 (sign of d killed by squaring).
__device__ __forceinline__ f32x2 dist3x2(f32x2 tx, f32x2 ty, f32x2 tz,
                                         f32x2 nqx, f32x2 nqy, f32x2 nqz) {
    f32x2 dx = pk_add(tx, nqx);
    f32x2 dy = pk_add(ty, nqy);
    f32x2 dz = pk_add(tz, nqz);
    f32x2 px = pk_mul(dx, dx);
    f32x2 py = pk_mul(dy, dy);
    f32x2 pz = pk_mul(dz, dz);
    return pk_add(pk_add(px, py), pz);
}

// ds_swizzle BitMode patterns: offset = (xor<<10) | (or<<5) | and, and=0x1F, or=0.
template <int PAT>
__device__ __forceinline__ float swzx(float x) {
    return __int_as_float(__builtin_amdgcn_ds_swizzle(__float_as_int(x), PAT));
}
static constexpr int SWZ_X1  = 0x041F;
static constexpr int SWZ_X2  = 0x081F;
static constexpr int SWZ_X4  = 0x101F;
static constexpr int SWZ_X8  = 0x201F;
static constexpr int SWZ_X16 = 0x401F;

__device__ __forceinline__ float dist3(float s0, float s1, float s2,
                                       float q0, float q1, float q2) {
    #pragma clang fp contract(off)
    float d0 = s0 - q0;
    float d1 = s1 - q1;
    float d2 = s2 - q2;
    return (d0 * d0 + d1 * d1) + d2 * d2;   // numpy-exact rounding order
}

__global__ __launch_bounds__(THR, 4) void cd_tile(const float* __restrict__ S,
                                                  const float* __restrict__ T,
                                                  unsigned long long* __restrict__ rowpart,
                                                  unsigned long long* __restrict__ colpart) {
    const int b = blockIdx.z;
    const int rbase = blockIdx.x * RT;
    const int cbase = blockIdx.y * CT;
    // Write-once partial planes (no atomics, no init):
    unsigned long long* rp = rowpart + (size_t)blockIdx.y * ENT + (size_t)b * Nn;
    unsigned long long* cp = colpart + (size_t)blockIdx.x * ENT + (size_t)b * Nn;

    __shared__ alignas(16) float lt[3][CT];             // SoA: x-plane, y-plane, z-plane
    __shared__ unsigned long long lwcol[4][CT];         // per-wave col minima, 2 KB
    if (threadIdx.x < CT * 3 / 4) {                     // 48 float4 loads, scatter to SoA
        float4 v4 = ((const float4*)(T + ((size_t)b * Nn + cbase) * 3))[threadIdx.x];
        int e = threadIdx.x * 4;
        lt[(e    ) % 3][(e    ) / 3] = v4.x;
        lt[(e + 1) % 3][(e + 1) / 3] = v4.y;
        lt[(e + 2) % 3][(e + 2) / 3] = v4.z;
        lt[(e + 3) % 3][(e + 3) / 3] = v4.w;
    }
    __syncthreads();

    const int w = threadIdx.x >> 6;
    const int L = threadIdx.x & 63;
    const int rowA = rbase + w * WROWS + L;        // + k*64, k<QPL
    const unsigned int anchor = (unsigned int)(rbase + w * WROWS);

    // Negated source coords, broadcast into both halves (t + (-q) = t - q).
    f32x2 nqx[QPL], nqy[QPL], nqz[QPL];
    #pragma unroll
    for (int k = 0; k < QPL; ++k) {
        const float* p = S + ((size_t)b * Nn + rowA + k * 64) * 3;
        float a0 = -p[0], a1 = -p[1], a2 = -p[2];
        nqx[k].x = a0; nqx[k].y = a0;
        nqy[k].x = a1; nqy[k].y = a1;
        nqz[k].x = a2; nqz[k].y = a2;
    }

    float best[QPL];
    int bb[QPL];
    #pragma unroll
    for (int k = 0; k < QPL; ++k) { best[k] = INFINITY; bb[k] = 0; }

    #pragma unroll 2
    for (int jb = 0; jb < CT / TB; ++jb) {
        const f32x2* lx = (const f32x2*)&lt[0][jb * TB];
        const f32x2* ly = (const f32x2*)&lt[1][jb * TB];
        const f32x2* lz = (const f32x2*)&lt[2][jb * TB];
        f32x2 tx[4], ty[4], tz[4];
        #pragma unroll
        for (int p = 0; p < 4; ++p) { tx[p] = lx[p]; ty[p] = ly[p]; tz[p] = lz[p]; }

        f32x2 cm2[4];   // col-side running minima: pair p covers cols {2p, 2p+1}
        #pragma unroll
        for (int k = 0; k < QPL; ++k) {
            f32x2 dd[4];
            #pragma unroll
            for (int p = 0; p < 4; ++p)
                dd[p] = dist3x2(tx[p], ty[p], tz[p], nqx[k], nqy[k], nqz[k]);
            #pragma unroll
            for (int p = 0; p < 4; ++p)
                cm2[p] = (k == 0) ? dd[p] : fmin2(cm2[p], dd[p]);
            // row side: exact associative min tree + strict <
            float m0 = fminf(fminf(dd[0].x, dd[0].y), dd[1].x);
            float m1 = fminf(fminf(dd[1].y, dd[2].x), dd[2].y);
            float m2 = fminf(dd[3].x, dd[3].y);
            float bmin = fminf(fminf(m0, m1), m2);
            if (bmin < best[k]) { best[k] = bmin; bb[k] = cbase + jb * TB; }
        }

        // View pair components in col order (register renaming only).
        float cmf0 = cm2[0].x, cmf1 = cm2[0].y, cmf2 = cm2[1].x, cmf3 = cm2[1].y;
        float cmf4 = cm2[2].x, cmf5 = cm2[2].y, cmf6 = cm2[3].x, cmf7 = cm2[3].y;

        // Fold-reduce 8 cols x 64 lanes -> lane L holds col 4*(L&1)+2*((L>>1)&1)+((L>>2)&1).
        // Exact: fmin only, any order gives the identical min value.
        const bool u1 = (L & 1);
        float a0 = fminf(u1 ? cmf4 : cmf0, swzx<SWZ_X1>(u1 ? cmf0 : cmf4));
        float a1 = fminf(u1 ? cmf5 : cmf1, swzx<SWZ_X1>(u1 ? cmf1 : cmf5));
        float a2 = fminf(u1 ? cmf6 : cmf2, swzx<SWZ_X1>(u1 ? cmf2 : cmf6));
        float a3 = fminf(u1 ? cmf7 : cmf3, swzx<SWZ_X1>(u1 ? cmf3 : cmf7));
        const bool u2 = (L & 2);
        float b0 = fminf(u2 ? a2 : a0, swzx<SWZ_X2>(u2 ? a0 : a2));
        float b1 = fminf(u2 ? a3 : a1, swzx<SWZ_X2>(u2 ? a1 : a3));
        const bool u4 = (L & 4);
        float c0 = fminf(u4 ? b1 : b0, swzx<SWZ_X4>(u4 ? b0 : b1));
        c0 = fminf(c0, swzx<SWZ_X8>(c0));
        c0 = fminf(c0, swzx<SWZ_X16>(c0));
        c0 = fminf(c0, __shfl_xor(c0, 32, 64));

        if (L < TB) {
            const int c = 4 * (L & 1) + 2 * ((L >> 1) & 1) + ((L >> 2) & 1);
            unsigned long long pk =
                ((unsigned long long)__float_as_uint(c0) << 32) | anchor;
            // Per-wave slot, written exactly once per block -> plain store, no atomic.
            lwcol[w][jb * TB + c] = pk;
        }
    }

    // Row side: ONE coalesced write-once store per (row, col-block). No init, no atomic.
    #pragma unroll
    for (int k = 0; k < QPL; ++k) {
        unsigned long long pk =
            ((unsigned long long)__float_as_uint(best[k]) << 32) |
            (unsigned int)bb[k];
        rp[rowA + k * 64] = pk;
    }

    // Col side: cross-wave min in LDS, then one write-once store per (col, row-block).
    __syncthreads();
    if (threadIdx.x < CT) {
        unsigned long long x0 = lwcol[0][threadIdx.x];
        unsigned long long x1 = lwcol[1][threadIdx.x];
        unsigned long long x2 = lwcol[2][threadIdx.x];
        unsigned long long x3 = lwcol[3][threadIdx.x];
        unsigned long long m01 = x0 < x1 ? x0 : x1;
        unsigned long long m23 = x2 < x3 ? x2 : x3;
        unsigned long long m = m01 < m23 ? m01 : m23;
        cp[cbase + threadIdx.x] = m;
    }
}

// Merged epilogue. Blocks [0,CB): col mode, 1 wave per col entry (u64-min sweep of 8
// row-block partials, then coalesced float4 rescan of the 256-row anchor range).
// Blocks [CB, CB+64): row mode, 1 thread per row entry (u64-min sweep of 128
// col-block partials, then float4 target-batch rescan). u64-min is a total order ->
// deterministic winner regardless of sweep order; ties pick smaller packed index,
// identical to the old atomicMin semantics.
__global__ __launch_bounds__(256) void cd_fin(const unsigned long long* __restrict__ rowpart,
                                              const unsigned long long* __restrict__ colpart,
                                              const float* __restrict__ S,
                                              const float* __restrict__ T,
                                              float* __restrict__ out,
                                              float* __restrict__ pr,
                                              float* __restrict__ pc) {
    __shared__ float red[4];
    const int tid = threadIdx.x;

    if (blockIdx.x < CB) {   // ---- col mode ----
        const int e = blockIdx.x * 4 + (tid >> 6);   // col entry [0, 16384)
        const int L = tid & 63;
        const int b = e >> 13;
        const int col = e & 8191;

        unsigned long long p = colpart[e];
        #pragma unroll
        for (int rb = 1; rb < NRB; ++rb) {
            unsigned long long q = colpart[(size_t)rb * ENT + e];
            p = q < p ? q : p;
        }
        const float m = __uint_as_float((unsigned int)(p >> 32));
        const int A = (int)(unsigned int)(p & 0xFFFFFFFFu);

        const float* tc = T + ((size_t)b * Nn + col) * 3;
        const float t0 = tc[0], t1 = tc[1], t2 = tc[2];

        const float4* Sp = (const float4*)(S + ((size_t)b * Nn + A + L * 4) * 3);
        const float4 x0 = Sp[0], x1 = Sp[1], x2 = Sp[2];   // 4 rows, coalesced

        int found = 0x7FFFFFFF;
        // descending r: last write wins -> smallest r; then int-min across lanes.
        if (dist3(x2.y, x2.z, x2.w, t0, t1, t2) == m) found = A + L * 4 + 3;
        if (dist3(x1.z, x1.w, x2.x, t0, t1, t2) == m) found = A + L * 4 + 2;
        if (dist3(x0.w, x1.x, x1.y, t0, t1, t2) == m) found = A + L * 4 + 1;
        if (dist3(x0.x, x0.y, x0.z, t0, t1, t2) == m) found = A + L * 4 + 0;
        #pragma unroll
        for (int mask = 1; mask < 64; mask <<= 1)
            found = min(found, __shfl_xor(found, mask, 64));
        if (L == 0) out[2 + 2 * Nn + e] = (float)found;

        if (L == 0) red[tid >> 6] = m;
        __syncthreads();
        if (tid == 0) pc[blockIdx.x] = (red[0] + red[1]) + (red[2] + red[3]);
    } else {                 // ---- row mode ----
        const int j = (blockIdx.x - CB) * 256 + tid;   // [0, 16384)
        const int b = j >> 13;
        const int row = j & 8191;

        unsigned long long p = rowpart[j];
        #pragma unroll 8
        for (int cb2 = 1; cb2 < NCB; ++cb2) {
            unsigned long long q = rowpart[(size_t)cb2 * ENT + j];
            p = q < p ? q : p;
        }
        const float dist = __uint_as_float((unsigned int)(p >> 32));
        const int cb = (int)(unsigned int)(p & 0xFFFFFFFFu);

        const float* Pp = S + ((size_t)b * Nn + row) * 3;
        const float s0 = Pp[0], s1 = Pp[1], s2 = Pp[2];
        const float4* Qb = (const float4*)(T + ((size_t)b * Nn + cb) * 3);  // cb%8==0 -> aligned
        const float4 y0 = Qb[0], y1 = Qb[1], y2 = Qb[2];
        const float4 y3 = Qb[3], y4 = Qb[4], y5 = Qb[5];

        int idx = cb;
        // descending t: last write wins -> smallest t attaining dist.
        if (dist3(s0, s1, s2, y5.y, y5.z, y5.w) == dist) idx = cb + 7;
        if (dist3(s0, s1, s2, y4.z, y4.w, y5.x) == dist) idx = cb + 6;
        if (dist3(s0, s1, s2, y3.w, y4.x, y4.y) == dist) idx = cb + 5;
        if (dist3(s0, s1, s2, y3.x, y3.y, y3.z) == dist) idx = cb + 4;
        if (dist3(s0, s1, s2, y2.y, y2.z, y2.w) == dist) idx = cb + 3;
        if (dist3(s0, s1, s2, y1.z, y1.w, y2.x) == dist) idx = cb + 2;
        if (dist3(s0, s1, s2, y0.w, y1.x, y1.y) == dist) idx = cb + 1;
        if (dist3(s0, s1, s2, y0.x, y0.y, y0.z) == dist) idx = cb + 0;
        out[2 + j] = (float)idx;

        float sum = dist;
        for (int off = 32; off > 0; off >>= 1) sum += __shfl_down(sum, off, 64);
        if ((tid & 63) == 0) red[tid >> 6] = sum;
        __syncthreads();
        if (tid == 0)
            pr[blockIdx.x - CB] = (red[0] + red[1]) + (red[2] + red[3]);
    }
}

// Deterministic parallel combine (fixed strided order).
__global__ __launch_bounds__(256) void cd_combine(const float* __restrict__ pr,
                                                  const float* __restrict__ pc,
                                                  float* __restrict__ out) {
    const int tid = threadIdx.x;
    float s1 = (tid < 64) ? pr[tid] : 0.0f;
    float s2 = 0.0f;
    for (int i = tid; i < CB; i += 256) s2 += pc[i];

    __shared__ float r1[4], r2[4];
    for (int off = 32; off > 0; off >>= 1) {
        s1 += __shfl_down(s1, off, 64);
        s2 += __shfl_down(s2, off, 64);
    }
    if ((tid & 63) == 0) { r1[tid >> 6] = s1; r2[tid >> 6] = s2; }
    __syncthreads();
    if (tid == 0) {
        out[0] = ((r1[0] + r1[1]) + (r1[2] + r1[3])) / (float)(Bn * Nn);
        out[1] = ((r2[0] + r2[1]) + (r2[2] + r2[3])) / (float)(Bn * Nn);
    }
}

// Fallback (no workspace): scan-all per query, direct writes + atomic loss.
static constexpr int FPTS = 256;
static constexpr int FCHUNK = 1024;

__global__ void cd_zero2(float* __restrict__ out) { out[0] = 0.0f; out[1] = 0.0f; }

__global__ __launch_bounds__(FPTS) void cd_dir_direct(const float* __restrict__ P,
                                                      const float* __restrict__ Q,
                                                      int nP, int nQ,
                                                      float* __restrict__ idx_out,
                                                      float* __restrict__ loss_out,
                                                      float inv_count) {
    __shared__ float lq[FCHUNK * 3];
    __shared__ float red[FPTS / 64];
    const int b = blockIdx.z;
    const int i = blockIdx.x * FPTS + threadIdx.x;
    const float* Pp = P + ((size_t)b * nP + i) * 3;
    const float s0 = Pp[0], s1 = Pp[1], s2 = Pp[2];

    float best = INFINITY;
    int bi = 0;
    for (int c = 0; c < nQ / FCHUNK; ++c) {
        __syncthreads();
        const float* Qb = Q + ((size_t)b * nQ + (size_t)c * FCHUNK) * 3;
        for (int j = threadIdx.x; j < FCHUNK * 3; j += FPTS) lq[j] = Qb[j];
        __syncthreads();
        #pragma unroll 4
        for (int m = 0; m < FCHUNK; ++m) {
            float dist = dist3(s0, s1, s2, lq[3 * m], lq[3 * m + 1], lq[3 * m + 2]);
            if (dist < best) { best = dist; bi = c * FCHUNK + m; }
        }
    }
    idx_out[(size_t)b * nP + i] = (float)bi;

    float v = best;
    for (int off = 32; off > 0; off >>= 1) v += __shfl_down(v, off, 64);
    const int wid = threadIdx.x >> 6;
    if ((threadIdx.x & 63) == 0) red[wid] = v;
    __syncthreads();
    if (threadIdx.x == 0) {
        float a = 0.0f;
        for (int w = 0; w < FPTS / 64; ++w) a += red[w];
        atomicAdd(loss_out, a * inv_count);
    }
}

extern "C" void kernel_launch(void* const* d_in, const int* in_sizes, int n_in,
                              void* d_out, int out_size, void* d_ws, size_t ws_size,
                              hipStream_t stream) {
    const float* src = (const float*)d_in[0];
    const float* tgt = (const float*)d_in[1];
    float* out = (float*)d_out;
    const size_t ROWP = (size_t)NCB * ENT;                 // 128*16384 u64 = 16.8 MB
    const size_t COLP = (size_t)NRB * ENT;                 // 8*16384 u64 = 1.05 MB
    const size_t need = (ROWP + COLP) * sizeof(unsigned long long)
                      + (64 + CB) * sizeof(float);

    if (ws_size >= need) {
        unsigned long long* rowpart = (unsigned long long*)d_ws;
        unsigned long long* colpart = rowpart + ROWP;
        float* pr = (float*)(colpart + COLP);              // 64 row partials
        float* pc = pr + 64;                               // 4096 col partials
        cd_tile<<<dim3(Nn / RT, Nn / CT, Bn), THR, 0, stream>>>(src, tgt, rowpart, colpart);
        cd_fin<<<CB + 64, 256, 0, stream>>>(rowpart, colpart, src, tgt, out, pr, pc);
        cd_combine<<<1, 256, 0, stream>>>(pr, pc, out);
    } else {
        cd_zero2<<<1, 1, 0, stream>>>(out);
        cd_dir_direct<<<dim3(Nn / FPTS, 1, Bn), FPTS, 0, stream>>>(
            src, tgt, Nn, Nn, out + 2, out + 0, 1.0f / (float)(Bn * Nn));
        cd_dir_direct<<<dim3(Nn / FPTS, 1, Bn), FPTS, 0, stream>>>(
            tgt, src, Nn, Nn, out + 2 + Bn * Nn, out + 1, 1.0f / (float)(Bn * Nn));
    }
}

// Round 7
// 53.489 us; speedup vs baseline: 1.2708x; 1.2708x over previous
//
#include <hip/hip_runtime.h>
#include <math.h>

// Chamfer distance, B=2, N=M=8192, C=3, fp32 — FUSED: each d(s_i,t_j) computed once,
// feeding both row-min (src->tgt) and col-min (tgt->src).
// d_out (float32): [loss_src, loss_dst, indices1 (B*N), indices2 (B*M)]
// ws: u64[32768]: [0,16384) row packed (dist<<32|colBatchBase), [16384,32768) col packed
//     (dist<<32|rowAnchor); then float pr[64], pc[4096].
//
// NOTE (R1): do NOT fuse the final combine via a last-block ticket — per-block
// __threadfence() on multi-XCD gfx950 = L2 writeback per block (4160 blocks -> 268 us).
// NOTE (R2): CT=128 (4 blocks/CU) LOST 2 us vs CT=64 (8 blocks/CU).
// NOTE (R3): __builtin_amdgcn_ds_swizzle pattern must be a literal -> template param.
// NOTE (R4): fold micro-opts flat.
// NOTE (R5): packed fp32 cut VALUBusy 78->58% with dur FLAT -> cd_tile not issue-bound;
// ~16 us of correlated stall bubbles absorb instruction savings.
// NOTE (R6): write-once partials + cd_fin sweep REGRESSED 13 us — partial planes are
// written/read on different XCDs (non-shared L2 -> 2x HBM round trips) and the 64
// row-sweep blocks are a serialized dispatch tail. Small hot atomics into L2 win.
// R7: the dominant per-wave serial latency is the 6-deep DS fold chain run 8x per
// wave. Hoist col-min accumulators across all jb (A[8][4] f32x2) and fold ONCE.

static constexpr int Bn = 2;
static constexpr int Nn = 8192;
static constexpr int THR = 256;    // 4 waves per block
static constexpr int QPL = 4;      // rows per lane
static constexpr int RT = 1024;    // rows per block; wave w owns [rbase+256w, +256)
static constexpr int WROWS = 256;  // rows per wave (QPL*64)
static constexpr int CT = 64;      // cols staged per block (8 blocks/CU, R2 lesson)
static constexpr int TB = 8;       // cols per register batch (4 f32x2 pairs)
static constexpr int NJB = CT / TB;   // 8 col batches
static constexpr int CB = 4096;    // col-mode blocks in cd_fin (4 cols/block, 1 wave/col)

typedef __attribute__((ext_vector_type(2))) float f32x2;

__device__ __forceinline__ f32x2 pk_add(f32x2 a, f32x2 b) {
    f32x2 r;
    asm("v_pk_add_f32 %0, %1, %2" : "=v"(r) : "v"(a), "v"(b));
    return r;
}
__device__ __forceinline__ f32x2 pk_mul(f32x2 a, f32x2 b) {
    f32x2 r;
    asm("v_pk_mul_f32 %0, %1, %2" : "=v"(r) : "v"(a), "v"(b));
    return r;
}
__device__ __forceinline__ f32x2 fmin2(f32x2 a, f32x2 b) {
    f32x2 r;
    r.x = fminf(a.x, b.x);
    r.y = fminf(a.y, b.y);
    return r;
}
// Squared distances of TWO target points vs one source point whose NEGATED coords are
// broadcast. Per component: ((dx*dx+dy*dy)+dz*dz), each op IEEE-rounded -> bitwise
// identical to scalar dist3 (sign of d killed by squaring).
__device__ __forceinline__ f32x2 dist3x2(f32x2 tx, f32x2 ty, f32x2 tz,
                                         f32x2 nqx, f32x2 nqy, f32x2 nqz) {
    f32x2 dx = pk_add(tx, nqx);
    f32x2 dy = pk_add(ty, nqy);
    f32x2 dz = pk_add(tz, nqz);
    f32x2 px = pk_mul(dx, dx);
    f32x2 py = pk_mul(dy, dy);
    f32x2 pz = pk_mul(dz, dz);
    return pk_add(pk_add(px, py), pz);
}

// ds_swizzle BitMode patterns: offset = (xor<<10) | (or<<5) | and, and=0x1F, or=0.
template <int PAT>
__device__ __forceinline__ float swzx(float x) {
    return __int_as_float(__builtin_amdgcn_ds_swizzle(__float_as_int(x), PAT));
}
static constexpr int SWZ_X1  = 0x041F;
static constexpr int SWZ_X2  = 0x081F;
static constexpr int SWZ_X4  = 0x101F;
static constexpr int SWZ_X8  = 0x201F;
static constexpr int SWZ_X16 = 0x401F;

__device__ __forceinline__ float dist3(float s0, float s1, float s2,
                                       float q0, float q1, float q2) {
    #pragma clang fp contract(off)
    float d0 = s0 - q0;
    float d1 = s1 - q1;
    float d2 = s2 - q2;
    return (d0 * d0 + d1 * d1) + d2 * d2;   // numpy-exact rounding order
}

__global__ void cd_init(unsigned long long* __restrict__ ws) {
    int i = blockIdx.x * blockDim.x + threadIdx.x;
    if (i < 2 * Bn * Nn) ws[i] = 0xFFFFFFFFFFFFFFFFULL;
}

__global__ __launch_bounds__(THR, 4) void cd_tile(const float* __restrict__ S,
                                                  const float* __restrict__ T,
                                                  unsigned long long* __restrict__ ws) {
    const int b = blockIdx.z;
    const int rbase = blockIdx.x * RT;
    const int cbase = blockIdx.y * CT;
    unsigned long long* wsRow = ws + (size_t)b * Nn;
    unsigned long long* wsCol = ws + 2 * Nn + (size_t)b * Nn;

    __shared__ alignas(16) float lt[3][CT];             // SoA: x-plane, y-plane, z-plane
    __shared__ unsigned long long lwcol[4][CT];         // per-wave col minima, 2 KB
    if (threadIdx.x < CT * 3 / 4) {                     // 48 float4 loads, scatter to SoA
        float4 v4 = ((const float4*)(T + ((size_t)b * Nn + cbase) * 3))[threadIdx.x];
        int e = threadIdx.x * 4;
        lt[(e    ) % 3][(e    ) / 3] = v4.x;
        lt[(e + 1) % 3][(e + 1) / 3] = v4.y;
        lt[(e + 2) % 3][(e + 2) / 3] = v4.z;
        lt[(e + 3) % 3][(e + 3) / 3] = v4.w;
    }
    __syncthreads();

    const int w = threadIdx.x >> 6;
    const int L = threadIdx.x & 63;
    const int rowA = rbase + w * WROWS + L;        // + k*64, k<QPL
    const unsigned int anchor = (unsigned int)(rbase + w * WROWS);

    // Negated source coords, broadcast into both halves (t + (-q) = t - q).
    f32x2 nqx[QPL], nqy[QPL], nqz[QPL];
    #pragma unroll
    for (int k = 0; k < QPL; ++k) {
        const float* p = S + ((size_t)b * Nn + rowA + k * 64) * 3;
        float a0 = -p[0], a1 = -p[1], a2 = -p[2];
        nqx[k].x = a0; nqx[k].y = a0;
        nqy[k].x = a1; nqy[k].y = a1;
        nqz[k].x = a2; nqz[k].y = a2;
    }

    float best[QPL];
    int bb[QPL];
    #pragma unroll
    for (int k = 0; k < QPL; ++k) { best[k] = INFINITY; bb[k] = 0; }

    // Col-min accumulators for ALL 64 cols: A[jb][p] covers cols (8jb+2p, 8jb+2p+1).
    // Fully-unrolled loops keep every index compile-time (no scratch).
    f32x2 A[NJB][4];

    #pragma unroll
    for (int jb = 0; jb < NJB; ++jb) {
        const f32x2* lx = (const f32x2*)&lt[0][jb * TB];
        const f32x2* ly = (const f32x2*)&lt[1][jb * TB];
        const f32x2* lz = (const f32x2*)&lt[2][jb * TB];
        f32x2 tx[4], ty[4], tz[4];
        #pragma unroll
        for (int p = 0; p < 4; ++p) { tx[p] = lx[p]; ty[p] = ly[p]; tz[p] = lz[p]; }

        #pragma unroll
        for (int k = 0; k < QPL; ++k) {
            f32x2 dd[4];
            #pragma unroll
            for (int p = 0; p < 4; ++p)
                dd[p] = dist3x2(tx[p], ty[p], tz[p], nqx[k], nqy[k], nqz[k]);
            #pragma unroll
            for (int p = 0; p < 4; ++p)
                A[jb][p] = (k == 0) ? dd[p] : fmin2(A[jb][p], dd[p]);
            // row side: exact associative min tree + strict <
            float m0 = fminf(fminf(dd[0].x, dd[0].y), dd[1].x);
            float m1 = fminf(fminf(dd[1].y, dd[2].x), dd[2].y);
            float m2 = fminf(dd[3].x, dd[3].y);
            float bmin = fminf(fminf(m0, m1), m2);
            if (bmin < best[k]) { best[k] = bmin; bb[k] = cbase + jb * TB; }
        }
    }

    // ---- ONE 64-col butterfly fold (6 steps, single DS-latency chain) ----
    // Invariant after step s: lane holds cols whose bits 0..s equal lane bits 0..s.
    // fmin-only tree: exact, order-free -> identical min values.
    const bool l0 = L & 1, l1 = L & 2, l2 = L & 4, l3 = L & 8, l4 = L & 16;
    float n0[NJB][4];                 // step 0: col bit0 == lane bit0 (32 values)
    #pragma unroll
    for (int j = 0; j < NJB; ++j)
        #pragma unroll
        for (int p = 0; p < 4; ++p) {
            float keep = l0 ? A[j][p].y : A[j][p].x;
            float send = l0 ? A[j][p].x : A[j][p].y;
            n0[j][p] = fminf(keep, swzx<SWZ_X1>(send));
        }
    float n1[NJB][2];                 // step 1: col bit1 (16 values)
    #pragma unroll
    for (int j = 0; j < NJB; ++j)
        #pragma unroll
        for (int p = 0; p < 2; ++p) {
            float keep = l1 ? n0[j][2 * p + 1] : n0[j][2 * p];
            float send = l1 ? n0[j][2 * p] : n0[j][2 * p + 1];
            n1[j][p] = fminf(keep, swzx<SWZ_X2>(send));
        }
    float n2[NJB];                    // step 2: col bit2 (8 values)
    #pragma unroll
    for (int j = 0; j < NJB; ++j) {
        float keep = l2 ? n1[j][1] : n1[j][0];
        float send = l2 ? n1[j][0] : n1[j][1];
        n2[j] = fminf(keep, swzx<SWZ_X4>(send));
    }
    float n3[4];                      // step 3: col bit3 (4 values)
    #pragma unroll
    for (int j = 0; j < 4; ++j) {
        float keep = l3 ? n2[2 * j + 1] : n2[2 * j];
        float send = l3 ? n2[2 * j] : n2[2 * j + 1];
        n3[j] = fminf(keep, swzx<SWZ_X8>(send));
    }
    float n4[2];                      // step 4: col bit4 (2 values)
    #pragma unroll
    for (int j = 0; j < 2; ++j) {
        float keep = l4 ? n3[2 * j + 1] : n3[2 * j];
        float send = l4 ? n3[2 * j] : n3[2 * j + 1];
        n4[j] = fminf(keep, swzx<SWZ_X16>(send));
    }
    // step 5: col bit5 == lane bit5, cross-32 via shfl.
    float keep5 = (L & 32) ? n4[1] : n4[0];
    float send5 = (L & 32) ? n4[0] : n4[1];
    float r = fminf(keep5, __shfl_xor(send5, 32, 64));
    // Lane L now holds the wave's min over its 256 rows for col (cbase + L).
    lwcol[w][L] = ((unsigned long long)__float_as_uint(r) << 32) | anchor;

    // Row side: one device atomic per (row, col-block).
    #pragma unroll
    for (int k = 0; k < QPL; ++k) {
        unsigned long long pk =
            ((unsigned long long)__float_as_uint(best[k]) << 32) |
            (unsigned int)bb[k];
        atomicMin(&wsRow[rowA + k * 64], pk);
    }

    // Col side: cross-wave min in LDS, then ONE device atomic per col per block.
    __syncthreads();
    if (threadIdx.x < CT) {
        unsigned long long x0 = lwcol[0][threadIdx.x];
        unsigned long long x1 = lwcol[1][threadIdx.x];
        unsigned long long x2 = lwcol[2][threadIdx.x];
        unsigned long long x3 = lwcol[3][threadIdx.x];
        unsigned long long m01 = x0 < x1 ? x0 : x1;
        unsigned long long m23 = x2 < x3 ? x2 : x3;
        unsigned long long m = m01 < m23 ? m01 : m23;
        atomicMin(&wsCol[cbase + threadIdx.x], m);
    }
}

// Merged epilogue. Blocks [0,CB): col mode, 1 wave per col entry (coalesced float4
// scan of the 256-row anchor range). Blocks [CB, CB+64): row mode, 1 thread per row
// entry (float4 target batch, descending == scan).
__global__ __launch_bounds__(256) void cd_fin(const unsigned long long* __restrict__ ws,
                                              const float* __restrict__ S,
                                              const float* __restrict__ T,
                                              float* __restrict__ out,
                                              float* __restrict__ pr,
                                              float* __restrict__ pc) {
    __shared__ float red[4];
    const int tid = threadIdx.x;

    if (blockIdx.x < CB) {   // ---- col mode ----
        const int e = blockIdx.x * 4 + (tid >> 6);   // col entry [0, 16384)
        const int L = tid & 63;
        const int b = e >> 13;
        const int col = e & 8191;

        unsigned long long p = ws[2 * Nn + e];
        const float m = __uint_as_float((unsigned int)(p >> 32));
        const int A = (int)(unsigned int)(p & 0xFFFFFFFFu);

        const float* tc = T + ((size_t)b * Nn + col) * 3;
        const float t0 = tc[0], t1 = tc[1], t2 = tc[2];

        const float4* Sp = (const float4*)(S + ((size_t)b * Nn + A + L * 4) * 3);
        const float4 x0 = Sp[0], x1 = Sp[1], x2 = Sp[2];   // 4 rows, coalesced

        int found = 0x7FFFFFFF;
        // descending r: last write wins -> smallest r; then int-min across lanes.
        if (dist3(x2.y, x2.z, x2.w, t0, t1, t2) == m) found = A + L * 4 + 3;
        if (dist3(x1.z, x1.w, x2.x, t0, t1, t2) == m) found = A + L * 4 + 2;
        if (dist3(x0.w, x1.x, x1.y, t0, t1, t2) == m) found = A + L * 4 + 1;
        if (dist3(x0.x, x0.y, x0.z, t0, t1, t2) == m) found = A + L * 4 + 0;
        #pragma unroll
        for (int mask = 1; mask < 64; mask <<= 1)
            found = min(found, __shfl_xor(found, mask, 64));
        if (L == 0) out[2 + 2 * Nn + e] = (float)found;

        if (L == 0) red[tid >> 6] = m;
        __syncthreads();
        if (tid == 0) pc[blockIdx.x] = (red[0] + red[1]) + (red[2] + red[3]);
    } else {                 // ---- row mode ----
        const int j = (blockIdx.x - CB) * 256 + tid;   // [0, 16384)
        const int b = j >> 13;
        const int row = j & 8191;

        unsigned long long p = ws[j];
        const float dist = __uint_as_float((unsigned int)(p >> 32));
        const int cb = (int)(unsigned int)(p & 0xFFFFFFFFu);

        const float* Pp = S + ((size_t)b * Nn + row) * 3;
        const float s0 = Pp[0], s1 = Pp[1], s2 = Pp[2];
        const float4* Qb = (const float4*)(T + ((size_t)b * Nn + cb) * 3);  // cb%8==0 -> aligned
        const float4 y0 = Qb[0], y1 = Qb[1], y2 = Qb[2];
        const float4 y3 = Qb[3], y4 = Qb[4], y5 = Qb[5];

        int idx = cb;
        // descending t: last write wins -> smallest t attaining dist.
        if (dist3(s0, s1, s2, y5.y, y5.z, y5.w) == dist) idx = cb + 7;
        if (dist3(s0, s1, s2, y4.z, y4.w, y5.x) == dist) idx = cb + 6;
        if (dist3(s0, s1, s2, y3.w, y4.x, y4.y) == dist) idx = cb + 5;
        if (dist3(s0, s1, s2, y3.x, y3.y, y3.z) == dist) idx = cb + 4;
        if (dist3(s0, s1, s2, y2.y, y2.z, y2.w) == dist) idx = cb + 3;
        if (dist3(s0, s1, s2, y1.z, y1.w, y2.x) == dist) idx = cb + 2;
        if (dist3(s0, s1, s2, y0.w, y1.x, y1.y) == dist) idx = cb + 1;
        if (dist3(s0, s1, s2, y0.x, y0.y, y0.z) == dist) idx = cb + 0;
        out[2 + j] = (float)idx;

        float sum = dist;
        for (int off = 32; off > 0; off >>= 1) sum += __shfl_down(sum, off, 64);
        if ((tid & 63) == 0) red[tid >> 6] = sum;
        __syncthreads();
        if (tid == 0)
            pr[blockIdx.x - CB] = (red[0] + red[1]) + (red[2] + red[3]);
    }
}

// Deterministic parallel combine (fixed strided order).
__global__ __launch_bounds__(256) void cd_combine(const float* __restrict__ pr,
                                                  const float* __restrict__ pc,
                                                  float* __restrict__ out) {
    const int tid = threadIdx.x;
    float s1 = (tid < 64) ? pr[tid] : 0.0f;
    float s2 = 0.0f;
    for (int i = tid; i < CB; i += 256) s2 += pc[i];

    __shared__ float r1[4], r2[4];
    for (int off = 32; off > 0; off >>= 1) {
        s1 += __shfl_down(s1, off, 64);
        s2 += __shfl_down(s2, off, 64);
    }
    if ((tid & 63) == 0) { r1[tid >> 6] = s1; r2[tid >> 6] = s2; }
    __syncthreads();
    if (tid == 0) {
        out[0] = ((r1[0] + r1[1]) + (r1[2] + r1[3])) / (float)(Bn * Nn);
        out[1] = ((r2[0] + r2[1]) + (r2[2] + r2[3])) / (float)(Bn * Nn);
    }
}

// Fallback (no workspace): scan-all per query, direct writes + atomic loss.
static constexpr int FPTS = 256;
static constexpr int FCHUNK = 1024;

__global__ void cd_zero2(float* __restrict__ out) { out[0] = 0.0f; out[1] = 0.0f; }

__global__ __launch_bounds__(FPTS) void cd_dir_direct(const float* __restrict__ P,
                                                      const float* __restrict__ Q,
                                                      int nP, int nQ,
                                                      float* __restrict__ idx_out,
                                                      float* __restrict__ loss_out,
                                                      float inv_count) {
    __shared__ float lq[FCHUNK * 3];
    __shared__ float red[FPTS / 64];
    const int b = blockIdx.z;
    const int i = blockIdx.x * FPTS + threadIdx.x;
    const float* Pp = P + ((size_t)b * nP + i) * 3;
    const float s0 = Pp[0], s1 = Pp[1], s2 = Pp[2];

    float best = INFINITY;
    int bi = 0;
    for (int c = 0; c < nQ / FCHUNK; ++c) {
        __syncthreads();
        const float* Qb = Q + ((size_t)b * nQ + (size_t)c * FCHUNK) * 3;
        for (int j = threadIdx.x; j < FCHUNK * 3; j += FPTS) lq[j] = Qb[j];
        __syncthreads();
        #pragma unroll 4
        for (int m = 0; m < FCHUNK; ++m) {
            float dist = dist3(s0, s1, s2, lq[3 * m], lq[3 * m + 1], lq[3 * m + 2]);
            if (dist < best) { best = dist; bi = c * FCHUNK + m; }
        }
    }
    idx_out[(size_t)b * nP + i] = (float)bi;

    float v = best;
    for (int off = 32; off > 0; off >>= 1) v += __shfl_down(v, off, 64);
    const int wid = threadIdx.x >> 6;
    if ((threadIdx.x & 63) == 0) red[wid] = v;
    __syncthreads();
    if (threadIdx.x == 0) {
        float a = 0.0f;
        for (int w = 0; w < FPTS / 64; ++w) a += red[w];
        atomicAdd(loss_out, a * inv_count);
    }
}

extern "C" void kernel_launch(void* const* d_in, const int* in_sizes, int n_in,
                              void* d_out, int out_size, void* d_ws, size_t ws_size,
                              hipStream_t stream) {
    const float* src = (const float*)d_in[0];
    const float* tgt = (const float*)d_in[1];
    float* out = (float*)d_out;
    const int TOTAL = 2 * Bn * Nn;                         // 32768 packed entries
    const size_t need = (size_t)TOTAL * sizeof(unsigned long long)
                      + (64 + CB) * sizeof(float);

    if (ws_size >= need) {
        unsigned long long* ws = (unsigned long long*)d_ws;
        float* pr = (float*)(ws + TOTAL);                  // 64 row partials
        float* pc = pr + 64;                               // 4096 col partials
        cd_init<<<(TOTAL + 255) / 256, 256, 0, stream>>>(ws);
        cd_tile<<<dim3(Nn / RT, Nn / CT, Bn), THR, 0, stream>>>(src, tgt, ws);
        cd_fin<<<CB + 64, 256, 0, stream>>>(ws, src, tgt, out, pr, pc);
        cd_combine<<<1, 256, 0, stream>>>(pr, pc, out);
    } else {
        cd_zero2<<<1, 1, 0, stream>>>(out);
        cd_dir_direct<<<dim3(Nn / FPTS, 1, Bn), FPTS, 0, stream>>>(
            src, tgt, Nn, Nn, out + 2, out + 0, 1.0f / (float)(Bn * Nn));
        cd_dir_direct<<<dim3(Nn / FPTS, 1, Bn), FPTS, 0, stream>>>(
            tgt, src, Nn, Nn, out + 2 + Bn * Nn, out + 1, 1.0f / (float)(Bn * Nn));
    }
}